// Round 9
// baseline (1185.343 us; speedup 1.0000x reference)
//
#include <hip/hip_runtime.h>
#include <hip/hip_bf16.h>
#include <math.h>

#define HID   1024
#define IN_D  600
#define IN_DP 640      // 600 padded to 10 x BK=64 chunks
#define BATCH 2048
#define TSTEP 20
#define BT    (BATCH * TSTEP)   // 40960
#define G3    3072

typedef __attribute__((ext_vector_type(8))) short bf16x8;
typedef __attribute__((ext_vector_type(4))) float f32x4;

#define GLB(p) ((const __attribute__((address_space(1))) void*)(p))
#define LDS(p) ((__attribute__((address_space(3))) void*)(p))

__device__ __forceinline__ short f2bf(float f) {
    __hip_bfloat16 b = __float2bfloat16(f);
    return *(short*)&b;
}
__device__ __forceinline__ float bf2f(short s) {
    __hip_bfloat16 b = *(__hip_bfloat16*)&s;
    return __bfloat162float(b);
}

// ---------------------------------------------------------------------------
// Input projection v2 (UNCHANGED from round 8: 204 us, MfmaUtil 34%,
// bank conflicts 0 — attribution isolation for the gru re-fusion).
// ---------------------------------------------------------------------------
__global__ __launch_bounds__(512) void gemm_input2(const short* __restrict__ X,
                                                   const short* __restrict__ Wih_r,
                                                   const float* __restrict__ b_ih,
                                                   short* __restrict__ gx) {
    __shared__ short LDSF[4 * 20480];   // buf b at b*20480: sA@0 (16K), sB@8192 (24K)

    const int id    = blockIdx.x;
    const int xcd   = id & 7;
    const int local = id >> 3;          // 0..639
    const int jsub  = local & 1;
    const int mblk  = local >> 1;       // 0..319
    const int j0 = (xcd * 2 + jsub) * 64;
    const int m0 = mblk * 128;

    const int tid  = threadIdx.x;
    const int wave = tid >> 6;          // 0..7
    const int lane = tid & 63;
    const int wm = (wave >> 2) * 64;    // m-group: 0 or 64
    const int jg = wave & 3;            // j-group: 16 j each
    const int fm = lane & 15;
    const int fq = lane >> 4;

    const int srow8 = lane >> 3;                // 0..7
    const int sxor  = ((lane & 7) ^ srow8) * 8; // inverse-swizzled col (shorts)

    const short* Wblk = Wih_r + (size_t)(j0 * 3) * IN_DP;   // 192 rows, K=640

    f32x4 acc[4][3] = {};    // [m-frag][gate]

    // 5 uniform global_load_lds per wave per chunk (2 sA + 3 sB)
    auto stage = [&](int kc, int bsel) {
        int k0 = kc * 64;
        short* base = LDSF + bsel * 20480;
#pragma unroll
        for (int i = 0; i < 2; ++i) {
            int row0 = wave * 16 + i * 8;
            const short* g = X + (size_t)(m0 + row0 + srow8) * IN_DP + k0 + sxor;
            __builtin_amdgcn_global_load_lds(GLB(g), LDS(base + row0 * 64), 16, 0, 0);
        }
#pragma unroll
        for (int i = 0; i < 3; ++i) {
            int row0 = wave * 24 + i * 8;
            const short* g = Wblk + (size_t)(row0 + srow8) * IN_DP + k0 + sxor;
            __builtin_amdgcn_global_load_lds(GLB(g), LDS(base + 8192 + row0 * 64), 16, 0, 0);
        }
    };

    stage(0, 0);
    stage(1, 1);

#pragma unroll
    for (int ic = 0; ic < 10; ++ic) {
        if (ic < 8) stage(ic + 2, (ic + 2) & 3);
        if (ic < 8)       asm volatile("s_waitcnt vmcnt(10)" : : : "memory");
        else if (ic == 8) asm volatile("s_waitcnt vmcnt(5)"  : : : "memory");
        else              asm volatile("s_waitcnt vmcnt(0)"  : : : "memory");
        __builtin_amdgcn_s_barrier();
        __builtin_amdgcn_sched_barrier(0);

        short* buf = LDSF + (ic & 3) * 20480;

#pragma unroll
        for (int kk = 0; kk < 2; ++kk) {
            bf16x8 af[4], bg[3];
            const int cbase = kk * 32 + fq * 8;
            const int csw = cbase ^ ((fm & 7) * 8);
#pragma unroll
            for (int mi = 0; mi < 4; ++mi)
                af[mi] = *(const bf16x8*)(&buf[(wm + mi * 16 + fm) * 64 + csw]);
#pragma unroll
            for (int g = 0; g < 3; ++g)
                bg[g] = *(const bf16x8*)(&buf[8192 + (jg * 48 + g * 16 + fm) * 64 + csw]);
            __builtin_amdgcn_s_setprio(1);
#pragma unroll
            for (int mi = 0; mi < 4; ++mi)
#pragma unroll
                for (int g = 0; g < 3; ++g)
                    acc[mi][g] = __builtin_amdgcn_mfma_f32_16x16x32_bf16(af[mi], bg[g], acc[mi][g], 0, 0, 0);
            __builtin_amdgcn_s_setprio(0);
        }
    }

    // Epilogue: gx[gm][g*1024 + j0 + jg*16 + fm] = bf16(acc + b_ih)
    const int jl = j0 + jg * 16 + fm;
#pragma unroll
    for (int g = 0; g < 3; ++g) {
        float bias = b_ih[g * HID + jl];
#pragma unroll
        for (int mi = 0; mi < 4; ++mi) {
#pragma unroll
            for (int r = 0; r < 4; ++r) {
                int gm = m0 + wm + mi * 16 + fq * 4 + r;
                gx[(size_t)gm * G3 + g * HID + jl] = f2bf(acc[mi][g][r] + bias);
            }
        }
    }
}

// ---------------------------------------------------------------------------
// v11: persistent 20-step kernel with XCD-LOCAL h exchange.
// v10 post-mortem: fusion overhead was the device-scope (SC1) h path — SC1
// bypasses L2 (no 64B dedup; IF$ latency per 16B request) + global spin ->
// 46 us/step. v7 per-step launches: 28 us/step (16 us kernel-boundary tax).
// v11 removes BOTH: partition batch rows by XCD (each XCD owns a 256-row
// m-stripe x ALL 1024 j via its 32 blocks = 2 mblk x 16 j-panels), so h is
// produced AND consumed within one XCD, where L2 IS the coherence point:
//  - h stores: plain (dirty local-L2 lines; consumers same-XCD).
//  - h loads: global_load_lds aux=1 (SC0) — bypasses only stale per-CU L1.
//  - NO SC1, NO threadfence, NO L2 invalidation. Wr/gx L1+L2-cacheable.
// blockIdx->XCD mapping is UNDEFINED (G16), so blocks SELF-ASSIGN:
// xcc = s_getreg(HW_REG_XCC_ID) [m09-verified] + per-XCD slot atomic.
// Co-residency of 256 x 160KB-LDS blocks (1/CU forced): proven by v8/v10.
// Release chain per step: epilogue stores -> vmcnt(0) -> __syncthreads ->
// tid0 relaxed agent atomicAdd (serializes at coherence point) -> consumer
// spin (relaxed agent load) -> __syncthreads -> SC0 h loads. Wave0's spin
// loads are vmcnt-drained inside the tid0 branch; ladder re-derived: wave0
// (9 outstanding) and others (15) both complete h0 at vmcnt(7), converge
// at ic=1. vmcnt: ic0=7, ic1..14=10, ic15=6, epilogue=0.
// ---------------------------------------------------------------------------
__global__ __launch_bounds__(512) void gru_fused(short* hb0, short* hb1,
                                                 const short* __restrict__ Wr,
                                                 const short* __restrict__ gx,
                                                 const float* __restrict__ b_hh,
                                                 float* __restrict__ out,
                                                 unsigned* __restrict__ cnt,
                                                 unsigned* __restrict__ xslot) {
    __shared__ short LDSF[4 * 20480];   // 160 KB: buf b at b*20480 (sA@0, sB@8192)
                                        // sGX tail-overlay at [0 .. 24576)

    const int tid  = threadIdx.x;
    const int wave = tid >> 6;          // 0..7
    const int lane = tid & 63;
    const int wm = (wave >> 2) * 64;    // m-group: 0 or 64
    const int jg = wave & 3;            // j-group: 16 j each
    const int fm = lane & 15;
    const int fq = lane >> 4;

    const int srow8 = lane >> 3;               // 0..7 (row within 8-row group)
    const int sxor  = ((lane & 7) ^ srow8) * 8; // inverse-swizzled col (shorts)

    // ---- physical-XCD self-assignment (mapping-independent, G16-safe) ----
    unsigned xcc;
    asm volatile("s_getreg_b32 %0, hwreg(HW_REG_XCC_ID)" : "=s"(xcc));
    if (tid == 0) {
        unsigned s = __hip_atomic_fetch_add(&xslot[xcc & 7], 1u,
                                            __ATOMIC_RELAXED,
                                            __HIP_MEMORY_SCOPE_AGENT);
        asm volatile("s_waitcnt vmcnt(0)" : : : "memory");
        *(volatile int*)LDSF = (int)s;
    }
    __syncthreads();
    const int slot = *(volatile int*)LDSF;   // 0..31 within this XCD
    __syncthreads();                          // all reads done before staging

    const int m0 = (int)(xcc & 7) * 256 + (slot >> 4) * 128;  // XCD m-stripe
    const int j0 = (slot & 15) * 64;                          // j-panel
    const int hchunk = slot & 15;       // k-chunk holding h[:, j0..j0+63]

    const short* Wblk = Wr + (size_t)(j0 * 3) * HID;   // 192 rows, K=1024
    const int jj = jg * 16 + fm;        // block-local j (0..63)
    const int jlane = j0 + jj;
    const float bh_r = b_hh[jlane];
    const float bh_i = b_hh[HID + jlane];
    const float bh_n = b_hh[2 * HID + jlane];

#pragma unroll 1
    for (int t = 0; t < TSTEP; ++t) {
        const short* hin  = (t & 1) ? hb1 : hb0;
        short*       hout = (t & 1) ? hb0 : hb1;
        const short* gxt  = gx + (size_t)t * BATCH * G3;

        // 3 Wr loads / wave / chunk — read-only, L1+L2 cacheable
        auto stageW = [&](int kc, int bsel) {
            int k0 = kc * 64;
            short* base = LDSF + bsel * 20480;
#pragma unroll
            for (int i = 0; i < 3; ++i) {
                int row0 = wave * 24 + i * 8;
                const short* g = Wblk + (size_t)(row0 + srow8) * HID + k0 + sxor;
                __builtin_amdgcn_global_load_lds(GLB(g), LDS(base + 8192 + row0 * 64), 16, 0, 0);
            }
        };
        // 2 h loads / wave / chunk — aux=1 (SC0): skip stale per-CU L1,
        // served from the XCD's L2 (which holds the producers' dirty lines).
        auto stageH = [&](int kc, int bsel) {
            int k0 = kc * 64;
            short* base = LDSF + bsel * 20480;
#pragma unroll
            for (int i = 0; i < 2; ++i) {
                int row0 = wave * 16 + i * 8;
                const short* g = hin + (size_t)(m0 + row0 + srow8) * HID + k0 + sxor;
                __builtin_amdgcn_global_load_lds(GLB(g), LDS(base + row0 * 64), 16, 0, 1);
            }
        };
        auto stage = [&](int kc, int bsel) { stageH(kc, bsel); stageW(kc, bsel); };
        // sGX instr q (0..47): gate q>>4, rows (q&15)*8..+7, 64 swizzled cols
        auto sgx_load = [&](int q) {
            int g = q >> 4;
            int row0 = (q & 15) * 8;
            const short* src = gxt + (size_t)(m0 + row0 + srow8) * G3 + g * HID + j0 + sxor;
            __builtin_amdgcn_global_load_lds(GLB(src), LDS(LDSF + q * 512), 16, 0, 0);
        };

        // ---- inter-step boundary --------------------------------------
        // Previous iteration ended with vmcnt(0) + __syncthreads: all h
        // stores are at L2 and all epilogue LDS reads retired -> safe to
        // overwrite buf0/buf1 sB and to signal arrival.
        stageW(0, 0);                      // fly during the spin (no h dep)
        stageW(1, 1);
        if (t > 0) {
            if (tid == 0) {
                __hip_atomic_fetch_add(&cnt[t * 32], 1u, __ATOMIC_RELAXED,
                                       __HIP_MEMORY_SCOPE_AGENT);
                while (__hip_atomic_load(&cnt[t * 32], __ATOMIC_RELAXED,
                                         __HIP_MEMORY_SCOPE_AGENT) < 256u)
                    __builtin_amdgcn_s_sleep(2);
                // drain wave0's atomic/spin loads so its vmcnt bookkeeping
                // rejoins the uniform ladder (also drains its Wr prefetch)
                asm volatile("s_waitcnt vmcnt(0)" : : : "memory");
            }
            __syncthreads();               // all producers arrived; h at L2
        }
        stageH(0, 0);
        stageH(1, 1);

        f32x4 acc[4][3] = {};    // [m-frag][gate]
        short hsnap[4][4];       // h[m-frag rows][this lane's j]

        // vmcnt ladder. ic0: wave0 has h0(2)+h1(2)+st2(5)=9, others have
        // Wr0(3)+Wr1(3)+h0(2)+h1(2)+st2(5)=15; vmcnt(7) completes h0 for
        // both. ic1: both at 12 -> vmcnt(10) completes h1; converged.
        // Steady vmcnt(10); ic15 vmcnt(6); epilogue vmcnt(0).
#pragma unroll
        for (int ic = 0; ic < 16; ++ic) {
            if (ic < 14) {
                stage(ic + 2, (ic + 2) & 3);
            } else if (ic == 14) {
#pragma unroll
                for (int i = 0; i < 5; ++i) sgx_load(wave * 5 + i);  // 40KB -> buf0
            } else {
                sgx_load(40 + wave);                  // 8KB -> buf1 head
            }
            if (ic == 0)       asm volatile("s_waitcnt vmcnt(7)"  : : : "memory");
            else if (ic < 15)  asm volatile("s_waitcnt vmcnt(10)" : : : "memory");
            else               asm volatile("s_waitcnt vmcnt(6)"  : : : "memory");
            __builtin_amdgcn_s_barrier();
            __builtin_amdgcn_sched_barrier(0);    // no reads hoist above publish

            short* buf = LDSF + (ic & 3) * 20480;

            if (ic == hchunk) {              // snapshot h[:, j0..j0+63]
#pragma unroll
                for (int mi = 0; mi < 4; ++mi)
#pragma unroll
                    for (int r = 0; r < 4; ++r) {
                        int mrow = wm + mi * 16 + fq * 4 + r;
                        hsnap[mi][r] = buf[mrow * 64 + (jj ^ ((mrow & 7) * 8))];
                    }
            }

#pragma unroll
            for (int kk = 0; kk < 2; ++kk) {
                bf16x8 af[4], bg[3];
                const int cbase = kk * 32 + fq * 8;
                const int csw = cbase ^ ((fm & 7) * 8);   // swizzled read col
#pragma unroll
                for (int mi = 0; mi < 4; ++mi)
                    af[mi] = *(const bf16x8*)(&buf[(wm + mi * 16 + fm) * 64 + csw]);
#pragma unroll
                for (int g = 0; g < 3; ++g)
                    bg[g] = *(const bf16x8*)(&buf[8192 + (jg * 48 + g * 16 + fm) * 64 + csw]);
                __builtin_amdgcn_s_setprio(1);
#pragma unroll
                for (int mi = 0; mi < 4; ++mi)
#pragma unroll
                    for (int g = 0; g < 3; ++g)
                        acc[mi][g] = __builtin_amdgcn_mfma_f32_16x16x32_bf16(af[mi], bg[g], acc[mi][g], 0, 0, 0);
                __builtin_amdgcn_s_setprio(0);
            }
        }

        // Drain sGX, publish within block, then epilogue: LDS/register-only
        // inputs; h out via plain stores (dirty local-L2 lines).
        asm volatile("s_waitcnt vmcnt(0)" : : : "memory");
        __builtin_amdgcn_s_barrier();
        __builtin_amdgcn_sched_barrier(0);

        const short* sGX = LDSF;            // [0 .. 24576) shorts
#pragma unroll
        for (int mi = 0; mi < 4; ++mi) {
#pragma unroll
            for (int r = 0; r < 4; ++r) {
                int mloc = wm + mi * 16 + fq * 4 + r;
                int gm = m0 + mloc;
                int jsw = jj ^ ((mloc & 7) * 8);          // sGX swizzled col
                float xr = bf2f(sGX[        mloc * 64 + jsw]);
                float xi = bf2f(sGX[ 8192 + mloc * 64 + jsw]);
                float xn = bf2f(sGX[16384 + mloc * 64 + jsw]);

                float rg = 1.0f / (1.0f + __expf(-(xr + acc[mi][0][r] + bh_r)));
                float ig = 1.0f / (1.0f + __expf(-(xi + acc[mi][1][r] + bh_i)));
                float ng = tanhf(xn + rg * (acc[mi][2][r] + bh_n));

                float h  = bf2f(hsnap[mi][r]);
                float hy = ng + ig * (h - ng);
                size_t idx = (size_t)gm * HID + jlane;
                hout[idx] = f2bf(hy);
                if (t == TSTEP - 1) out[idx] = hy;
            }
        }

        if (t < TSTEP - 1) {
            asm volatile("s_waitcnt vmcnt(0)" : : : "memory");  // h at L2
            __syncthreads();    // epilogue LDS reads done; release complete
        }
    }
}

// x [b][t][600] fp32 -> x_bf [t*B + b][640] bf16 zero-padded (transpose)
__global__ __launch_bounds__(256) void cvt_x(const float* __restrict__ X, short* __restrict__ Xb) {
    int rd = blockIdx.x;             // dst row = t*BATCH + b
    int tt = rd >> 11;               // /2048
    int b  = rd & (BATCH - 1);
    const float* s = X + ((size_t)b * TSTEP + tt) * IN_D;
    short* d = Xb + (size_t)rd * IN_DP;
    for (int c = threadIdx.x; c < IN_DP; c += 256)
        d[c] = (c < IN_D) ? f2bf(s[c]) : (short)0;
}

// W_ih -> gate-block-interleaved bf16 [3072][640]:
// dst row jb*48+g*16+ji = W_ih[g*1024 + jb*16 + ji], zero-padded K 600->640
__global__ __launch_bounds__(256) void cvt_wih_r(const float* __restrict__ W, short* __restrict__ Wb) {
    int n  = blockIdx.x;             // dst row 0..3071
    int jb = n / 48;
    int rem = n - jb * 48;
    int g  = rem >> 4;
    int ji = rem & 15;
    const float* s = W + (size_t)(g * HID + jb * 16 + ji) * IN_D;
    short* d = Wb + (size_t)n * IN_DP;
    for (int c = threadIdx.x; c < IN_DP; c += 256)
        d[c] = (c < IN_D) ? f2bf(s[c]) : (short)0;
}

// W_hh -> Wr gate-block-interleaved bf16: Wr[jb*48+g*16+ji] = Whh[g*1024+jb*16+ji]
__global__ __launch_bounds__(256) void cvt_whh(const float* __restrict__ W, short* __restrict__ Wr) {
    int n  = blockIdx.x;             // dst row 0..3071
    int jb = n / 48;
    int rem = n - jb * 48;
    int g  = rem >> 4;
    int ji = rem & 15;
    const float* s = W + (size_t)(g * HID + jb * 16 + ji) * HID;
    short* d = Wr + (size_t)n * HID;
    for (int c = threadIdx.x; c < HID; c += 256) d[c] = f2bf(s[c]);
}

extern "C" void kernel_launch(void* const* d_in, const int* in_sizes, int n_in,
                              void* d_out, int out_size, void* d_ws, size_t ws_size,
                              hipStream_t stream) {
    const float* x    = (const float*)d_in[0];  // [B, T, IN_D]
    const float* W_ih = (const float*)d_in[1];  // [3H, IN_D]
    const float* b_ih = (const float*)d_in[2];
    const float* W_hh = (const float*)d_in[3];  // [3H, HID]
    const float* b_hh = (const float*)d_in[4];
    float* out = (float*)d_out;                 // [B, HID]

    char* p = (char*)d_ws;
    short* gx     = (short*)p;  p += (size_t)BT * G3 * 2;       // 251.7 MB, [t][b][3H]
    short* x_bf   = (short*)p;  p += (size_t)BT * IN_DP * 2;    //  52.4 MB, [t][b][640]
    short* hb0    = (short*)p;  p += (size_t)BATCH * HID * 2;   //   4.2 MB
    short* hb1    = (short*)p;  p += (size_t)BATCH * HID * 2;   //   4.2 MB
    short* Wih_r  = (short*)p;  p += (size_t)G3 * IN_DP * 2;    //   3.9 MB
    short* Whh_r  = (short*)p;  p += (size_t)G3 * HID * 2;      //   6.3 MB
    unsigned* cnt   = (unsigned*)p; p += 20 * 32 * 4;           // per-step barrier
    unsigned* xslot = (unsigned*)p; p += 8 * 4;                 // per-XCD slots
    // total ~323 MB

    cvt_wih_r<<<G3, 256, 0, stream>>>(W_ih, Wih_r);
    cvt_whh<<<G3, 256, 0, stream>>>(W_hh, Whh_r);
    cvt_x<<<BT, 256, 0, stream>>>(x, x_bf);
    hipMemsetAsync(hb0, 0, (size_t)BATCH * HID * 2, stream);
    hipMemsetAsync(cnt, 0, 20 * 32 * 4 + 8 * 4, stream);        // cnt + xslot

    // Input projection, counted-vmcnt pipeline (5120 blocks x 512 threads)
    gemm_input2<<<5120, 512, 0, stream>>>(x_bf, Wih_r, b_ih, gx);

    // All 20 recurrent steps in one persistent kernel (1 block/CU x 256),
    // XCD-local h exchange via self-assigned stripes.
    gru_fused<<<256, 512, 0, stream>>>(hb0, hb1, Whh_r, gx, b_hh, out, cnt, xslot);
}